// Round 1
// baseline (377.507 us; speedup 1.0000x reference)
//
#include <hip/hip_runtime.h>
#include <stdint.h>

#define NUM_UNIQUE   256
#define NUM_SAMPLES  4096
#define NUM_QUBITS   64
#define BATCH_SIZE   1024
#define THREADS      1024
#define WAVES        (THREADS / 64)
#define CHUNKS       (NUM_SAMPLES / 64)      // 64 chunks of 64 samples
#define CHUNKS_PER_WAVE (CHUNKS / WAVES)     // 4

// Block = one unique circuit. 16 waves, each handles 4 chunks of 64 samples.
// Per chunk: bit-pack sample bits -> ballot-transpose to qubit-major words ->
// xor/popcount pair loop contracted with K (in LDS). Exact integer Gram.
__global__ __launch_bounds__(THREADS)
void energy_kernel(const int* __restrict__ samples,
                   const float* __restrict__ bias,
                   const float* __restrict__ Kmat,
                   float* __restrict__ uniq)
{
    __shared__ float Klds[NUM_QUBITS * 65];                 // +1 pad: bank = (q + r) % 32
    __shared__ unsigned long long words[WAVES][64];
    __shared__ float wsum[WAVES];

    const int tid  = threadIdx.x;
    const int wave = tid >> 6;
    const int lane = tid & 63;
    const int c    = blockIdx.x;

    // Stage K (4096 floats) into padded LDS
    for (int t = tid; t < NUM_QUBITS * NUM_QUBITS; t += THREADS)
        Klds[(t >> 6) * 65 + (t & 63)] = Kmat[t];
    __syncthreads();

    float accQ = 0.0f;   // sum over chunks,r of K[q,r] * sum_s s_q s_r   (q = lane)
    int   cnt  = 0;      // ones count of qubit q over this wave's samples

    for (int ci = 0; ci < CHUNKS_PER_WAVE; ++ci) {
        const int chunk = wave * CHUNKS_PER_WAVE + ci;      // 0..63
        const int4* sp = (const int4*)(samples +
            ((size_t)c * NUM_SAMPLES + (size_t)(chunk * 64 + lane)) * NUM_QUBITS);

        // Pack this lane's sample (64 int32 bits) into one uint64
        unsigned long long w = 0ull;
        #pragma unroll
        for (int i = 0; i < 16; ++i) {
            int4 v = sp[i];
            w |= ((unsigned long long)(v.x & 1)) << (4 * i + 0);
            w |= ((unsigned long long)(v.y & 1)) << (4 * i + 1);
            w |= ((unsigned long long)(v.z & 1)) << (4 * i + 2);
            w |= ((unsigned long long)(v.w & 1)) << (4 * i + 3);
        }

        // Transpose: lane q ends up holding B_q (bit s = sample s's qubit q)
        unsigned long long myB = 0ull;
        #pragma unroll
        for (int q = 0; q < 64; ++q) {
            unsigned long long bq = __ballot((unsigned int)((w >> q) & 1ull));
            myB = (lane == q) ? bq : myB;
        }

        __syncthreads();                 // prior iteration's reads complete
        words[wave][lane] = myB;
        __syncthreads();                 // writes visible (also intra-wave ordering)

        cnt += (int)__popcll(myB);

        const float* Krow = &Klds[lane * 65];
        #pragma unroll
        for (int r = 0; r < 64; ++r) {
            unsigned long long br = words[wave][r];
            int pc = (int)__popcll(myB ^ br);
            // sum_{s in chunk} s_q * s_r = 64 - 2*popcount(B_q ^ B_r)  (exact)
            accQ = fmaf(Krow[r], (float)(64 - 2 * pc), accQ);
        }
    }

    // linear term: sum_s s_q = (#samples this wave) - 2*cnt
    float contrib = accQ +
        bias[lane] * (float)(CHUNKS_PER_WAVE * 64 - 2 * cnt);

    // reduce 64 lanes
    #pragma unroll
    for (int off = 32; off > 0; off >>= 1)
        contrib += __shfl_down(contrib, off);

    if (lane == 0) wsum[wave] = contrib;
    __syncthreads();
    if (tid == 0) {
        float s = 0.0f;
        #pragma unroll
        for (int i = 0; i < WAVES; ++i) s += wsum[i];
        uniq[c] = s * (1.0f / NUM_SAMPLES);   // mean over samples (exact pow2 scale)
    }
}

__global__ void gather_kernel(const float* __restrict__ uniq,
                              const int* __restrict__ idx,
                              float* __restrict__ out)
{
    int b = blockIdx.x * blockDim.x + threadIdx.x;
    if (b < BATCH_SIZE) out[b] = uniq[idx[b]];
}

extern "C" void kernel_launch(void* const* d_in, const int* in_sizes, int n_in,
                              void* d_out, int out_size, void* d_ws, size_t ws_size,
                              hipStream_t stream)
{
    const int*   samples = (const int*)d_in[0];
    const int*   idx     = (const int*)d_in[1];
    const float* bias    = (const float*)d_in[2];
    const float* Kmat    = (const float*)d_in[3];
    float* out  = (float*)d_out;
    float* uniq = (float*)d_ws;   // 256 floats of scratch

    energy_kernel<<<NUM_UNIQUE, THREADS, 0, stream>>>(samples, bias, Kmat, uniq);
    gather_kernel<<<(BATCH_SIZE + 255) / 256, 256, 0, stream>>>(uniq, idx, out);
}

// Round 2
// 371.372 us; speedup vs baseline: 1.0165x; 1.0165x over previous
//
#include <hip/hip_runtime.h>
#include <stdint.h>

#define NUM_UNIQUE   256
#define NUM_SAMPLES  4096
#define NUM_QUBITS   64
#define BATCH_SIZE   1024
#define THREADS      1024
#define WAVES        (THREADS / 64)
#define CHUNKS       (NUM_SAMPLES / 64)      // 64 chunks of 64 samples
#define CHUNKS_PER_WAVE (CHUNKS / WAVES)     // 4

// Block = one unique circuit (grid 256 = 1 block/CU). 16 waves, each wave
// owns 4 chunks of 64 samples, no barriers in the main loop.
//
// Per chunk (16 KB, contiguous):
//   1. 16 fully-coalesced dwordx4 loads: iter i, lane l -> ints [256i+4l ..+3]
//      => lane l sees sample 4i+(l>>4), qubits 4(l&15)..+3. 1 KB/instruction.
//   2. Pack bits into four 16-bit masks (one per qubit of the lane's block).
//   3. 4-step __shfl transpose: lane q ends with B_q = 64 samples' bit of
//      qubit q (sample ordering permuted, but identically for every q).
//   4. Gram via xor+popcount: sum_s s_q s_r = 64 - 2*popcount(B_q^B_r).
//      Refactored: sum_r K[q,r]*(64-2pc) = 64*rowsumK[q] - 2*sum_r K[q,r]*pc.
__global__ __launch_bounds__(THREADS)
void energy_kernel(const int* __restrict__ samples,
                   const float* __restrict__ bias,
                   const float* __restrict__ Kmat,
                   float* __restrict__ uniq)
{
    __shared__ float Klds[NUM_QUBITS * 65];             // +1 pad: bank=(q+r)%32, 2-way=free
    __shared__ unsigned long long words[WAVES][64];     // per-wave private
    __shared__ float wsum[WAVES];

    const int tid  = threadIdx.x;
    const int wave = tid >> 6;
    const int lane = tid & 63;
    const int c    = blockIdx.x;

    for (int t = tid; t < NUM_QUBITS * NUM_QUBITS; t += THREADS)
        Klds[(t >> 6) * 65 + (t & 63)] = Kmat[t];
    __syncthreads();

    // row sum of K for this lane's qubit q = lane
    const float* Krow = &Klds[lane * 65];
    float rowsum = 0.0f;
    #pragma unroll
    for (int r = 0; r < 64; ++r) rowsum += Krow[r];

    float pcacc = 0.0f;   // sum over chunks,r of K[q,r] * popcount(B_q^B_r)
    int   cnt   = 0;      // ones of qubit q over this wave's 256 samples

    for (int ci = 0; ci < CHUNKS_PER_WAVE; ++ci) {
        const int chunk = wave * CHUNKS_PER_WAVE + ci;
        const int4* cp = (const int4*)(samples +
            ((size_t)c * NUM_SAMPLES + (size_t)chunk * 64) * NUM_QUBITS);

        // ---- coalesced load + bit pack ----
        unsigned int m0 = 0, m1 = 0, m2 = 0, m3 = 0;
        #pragma unroll
        for (int i = 0; i < 16; ++i) {
            int4 v = cp[i * 64 + lane];          // 1 KB contiguous per wave-instr
            m0 = (m0 << 1) | (unsigned int)(v.x & 1);
            m1 = (m1 << 1) | (unsigned int)(v.y & 1);
            m2 = (m2 << 1) | (unsigned int)(v.z & 1);
            m3 = (m3 << 1) | (unsigned int)(v.w & 1);
        }
        unsigned long long W = (unsigned long long)m0
                             | ((unsigned long long)m1 << 16)
                             | ((unsigned long long)m2 << 32)
                             | ((unsigned long long)m3 << 48);

        // ---- transpose: lane q gathers its qubit's bits from 4 lanes ----
        unsigned long long B = 0ull;
        #pragma unroll
        for (int p = 0; p < 4; ++p) {
            unsigned long long src = __shfl(W, 16 * p + (lane >> 2));
            B |= ((src >> (16 * (lane & 3))) & 0xFFFFull) << (16 * p);
        }

        cnt += (int)__popcll(B);
        words[wave][lane] = B;                   // same-wave write->read, no barrier

        // ---- Gram pair loop: broadcast B_r, private K row ----
        const unsigned long long* wp = words[wave];
        #pragma unroll
        for (int r = 0; r < 64; ++r) {
            unsigned long long br = wp[r];       // same-address broadcast, conflict-free
            int pc = (int)__popcll(B ^ br);
            pcacc = fmaf(Krow[r], (float)pc, pcacc);
        }
    }

    // quad: 64*nchunks*rowsum - 2*pcacc ; linear: bias_q * (256 - 2*cnt)
    float contrib = 64.0f * (float)CHUNKS_PER_WAVE * rowsum - 2.0f * pcacc
                  + bias[lane] * (float)(CHUNKS_PER_WAVE * 64 - 2 * cnt);

    #pragma unroll
    for (int off = 32; off > 0; off >>= 1)
        contrib += __shfl_down(contrib, off);

    if (lane == 0) wsum[wave] = contrib;
    __syncthreads();
    if (tid == 0) {
        float s = 0.0f;
        #pragma unroll
        for (int i = 0; i < WAVES; ++i) s += wsum[i];
        uniq[c] = s * (1.0f / NUM_SAMPLES);
    }
}

__global__ void gather_kernel(const float* __restrict__ uniq,
                              const int* __restrict__ idx,
                              float* __restrict__ out)
{
    int b = blockIdx.x * blockDim.x + threadIdx.x;
    if (b < BATCH_SIZE) out[b] = uniq[idx[b]];
}

extern "C" void kernel_launch(void* const* d_in, const int* in_sizes, int n_in,
                              void* d_out, int out_size, void* d_ws, size_t ws_size,
                              hipStream_t stream)
{
    const int*   samples = (const int*)d_in[0];
    const int*   idx     = (const int*)d_in[1];
    const float* bias    = (const float*)d_in[2];
    const float* Kmat    = (const float*)d_in[3];
    float* out  = (float*)d_out;
    float* uniq = (float*)d_ws;   // 256 floats of scratch

    energy_kernel<<<NUM_UNIQUE, THREADS, 0, stream>>>(samples, bias, Kmat, uniq);
    gather_kernel<<<(BATCH_SIZE + 255) / 256, 256, 0, stream>>>(uniq, idx, out);
}

// Round 3
// 352.189 us; speedup vs baseline: 1.0719x; 1.0545x over previous
//
#include <hip/hip_runtime.h>
#include <stdint.h>

#define NUM_UNIQUE   256
#define NUM_SAMPLES  4096
#define NUM_QUBITS   64
#define BATCH_SIZE   1024
#define THREADS      1024
#define WAVES        (THREADS / 64)
#define CHUNKS       (NUM_SAMPLES / 64)      // 64 chunks of 64 samples
#define CHUNKS_PER_WAVE (CHUNKS / WAVES)     // 4

typedef int v4i __attribute__((ext_vector_type(4)));

// Block = one unique circuit. 16 waves x 4 chunks of 64 samples.
// R3 change vs R2: break device-wide channel lockstep ("convoy") —
//  (a) per-(block,wave) rotation of the 16-load sequence inside each chunk,
//  (b) per-block rotation of chunk order,
//  (c) nontemporal loads (read-once 268 MB stream).
// Compute path identical to R2 (exact integer Gram via xor+popcount);
// rotations only permute sample order, identically for every lane of a wave.
__global__ __launch_bounds__(THREADS)
void energy_kernel(const int* __restrict__ samples,
                   const float* __restrict__ bias,
                   const float* __restrict__ Kmat,
                   float* __restrict__ uniq)
{
    __shared__ float Klds[NUM_QUBITS * 65];             // +1 pad: 2-way = free
    __shared__ unsigned long long words[WAVES][64];     // per-wave private
    __shared__ float wsum[WAVES];

    const int tid  = threadIdx.x;
    const int wave = tid >> 6;
    const int lane = tid & 63;
    const int c    = blockIdx.x;

    for (int t = tid; t < NUM_QUBITS * NUM_QUBITS; t += THREADS)
        Klds[(t >> 6) * 65 + (t & 63)] = Kmat[t];
    __syncthreads();

    const float* Krow = &Klds[lane * 65];
    float rowsum = 0.0f;
    #pragma unroll
    for (int r = 0; r < 64; ++r) rowsum += Krow[r];

    float pcacc = 0.0f;   // sum over chunks,r of K[q,r] * popcount(B_q^B_r)
    int   cnt   = 0;      // ones of qubit q over this wave's 256 samples

    const int loadrot  = (3 * wave + 5 * c) & 15;   // intra-chunk phase stagger
    const int chunkrot = (13 * c) & 63;             // chunk-order stagger

    for (int ci = 0; ci < CHUNKS_PER_WAVE; ++ci) {
        const int chunk = ((wave * CHUNKS_PER_WAVE + ci) + chunkrot) & 63;
        const v4i* cp = (const v4i*)(samples +
            ((size_t)c * NUM_SAMPLES + (size_t)chunk * 64) * NUM_QUBITS);

        // ---- coalesced, phase-staggered load + bit pack ----
        // iter i loads slice j=(i+loadrot)&15: 1 KB contiguous per wave-instr,
        // concurrent wave-instrs across the device spread over the whole 16 KB
        // chunk period instead of hitting the same 1 KB offset in lockstep.
        unsigned int m0 = 0, m1 = 0, m2 = 0, m3 = 0;
        #pragma unroll
        for (int i = 0; i < 16; ++i) {
            const int j = (i + loadrot) & 15;
            v4i v = __builtin_nontemporal_load(cp + j * 64 + lane);
            m0 = (m0 << 1) | (unsigned int)(v.x & 1);
            m1 = (m1 << 1) | (unsigned int)(v.y & 1);
            m2 = (m2 << 1) | (unsigned int)(v.z & 1);
            m3 = (m3 << 1) | (unsigned int)(v.w & 1);
        }
        unsigned long long W = (unsigned long long)m0
                             | ((unsigned long long)m1 << 16)
                             | ((unsigned long long)m2 << 32)
                             | ((unsigned long long)m3 << 48);

        // ---- 4-step shuffle transpose: lane q ends with B_q ----
        unsigned long long B = 0ull;
        #pragma unroll
        for (int p = 0; p < 4; ++p) {
            unsigned long long src = __shfl(W, 16 * p + (lane >> 2));
            B |= ((src >> (16 * (lane & 3))) & 0xFFFFull) << (16 * p);
        }

        cnt += (int)__popcll(B);
        words[wave][lane] = B;                   // same-wave write->read, no barrier

        // ---- Gram pair loop: broadcast B_r, private K row ----
        const unsigned long long* wp = words[wave];
        #pragma unroll
        for (int r = 0; r < 64; ++r) {
            unsigned long long br = wp[r];       // same-address broadcast
            int pc = (int)__popcll(B ^ br);
            pcacc = fmaf(Krow[r], (float)pc, pcacc);
        }
    }

    // quad: 64*nchunks*rowsum - 2*pcacc ; linear: bias_q * (256 - 2*cnt)
    float contrib = 64.0f * (float)CHUNKS_PER_WAVE * rowsum - 2.0f * pcacc
                  + bias[lane] * (float)(CHUNKS_PER_WAVE * 64 - 2 * cnt);

    #pragma unroll
    for (int off = 32; off > 0; off >>= 1)
        contrib += __shfl_down(contrib, off);

    if (lane == 0) wsum[wave] = contrib;
    __syncthreads();
    if (tid == 0) {
        float s = 0.0f;
        #pragma unroll
        for (int i = 0; i < WAVES; ++i) s += wsum[i];
        uniq[c] = s * (1.0f / NUM_SAMPLES);
    }
}

__global__ void gather_kernel(const float* __restrict__ uniq,
                              const int* __restrict__ idx,
                              float* __restrict__ out)
{
    int b = blockIdx.x * blockDim.x + threadIdx.x;
    if (b < BATCH_SIZE) out[b] = uniq[idx[b]];
}

extern "C" void kernel_launch(void* const* d_in, const int* in_sizes, int n_in,
                              void* d_out, int out_size, void* d_ws, size_t ws_size,
                              hipStream_t stream)
{
    const int*   samples = (const int*)d_in[0];
    const int*   idx     = (const int*)d_in[1];
    const float* bias    = (const float*)d_in[2];
    const float* Kmat    = (const float*)d_in[3];
    float* out  = (float*)d_out;
    float* uniq = (float*)d_ws;   // 256 floats of scratch

    energy_kernel<<<NUM_UNIQUE, THREADS, 0, stream>>>(samples, bias, Kmat, uniq);
    gather_kernel<<<(BATCH_SIZE + 255) / 256, 256, 0, stream>>>(uniq, idx, out);
}